// Round 4
// baseline (648.931 us; speedup 1.0000x reference)
//
#include <hip/hip_runtime.h>
#include <stdint.h>

typedef unsigned short u16;
typedef __attribute__((ext_vector_type(8))) short short8;
typedef __attribute__((ext_vector_type(4))) float f32x4;

#define MFMA_BF16(a,b,c) __builtin_amdgcn_mfma_f32_16x16x32_bf16((a),(b),(c),0,0,0)

#define S_BARRIER()  asm volatile("s_barrier" ::: "memory")
#define WAIT_LGKM0() asm volatile("s_waitcnt lgkmcnt(0)" ::: "memory")
#define WAIT_VM(N)   asm volatile("s_waitcnt vmcnt(" #N ")" ::: "memory")

__device__ __forceinline__ u16 f2bf(float x) {
    uint32_t u = __builtin_bit_cast(uint32_t, x);
    u += 0x7fffu + ((u >> 16) & 1u);   // RNE
    return (u16)(u >> 16);
}
__device__ __forceinline__ float bf2f(u16 u) {
    return __builtin_bit_cast(float, (uint32_t)u << 16);
}
// async global->LDS, 16B per lane; LDS dest = wave-uniform base + lane*16
__device__ __forceinline__ void glds16(const void* g, void* lds) {
    __builtin_amdgcn_global_load_lds((const __attribute__((address_space(1))) void*)g,
                                     (__attribute__((address_space(3))) void*)lds,
                                     16, 0, 0);
}

// ---------------- fused fp32 -> bf16 convert (all 5 tensors, 1 launch) ----
__device__ __forceinline__ void cvt4(const float* __restrict__ s,
                                     u16* __restrict__ d, int i) {
    float4 v = *(const float4*)(s + i);
    ushort4 o;
    o.x = f2bf(v.x); o.y = f2bf(v.y); o.z = f2bf(v.z); o.w = f2bf(v.w);
    *(ushort4*)(d + i) = o;
}
__global__ __launch_bounds__(256) void cvt_all(
        const float* __restrict__ s0, u16* __restrict__ d0,   // hidden 10485760
        const float* __restrict__ s1, u16* __restrict__ d1,   // wq     10485760
        const float* __restrict__ s2, u16* __restrict__ d2,   // wk      2621440
        const float* __restrict__ s3, u16* __restrict__ d3,   // wv      2621440
        const float* __restrict__ s4, u16* __restrict__ d4)   // wo     10485760
{
    int i = (blockIdx.x * 256 + threadIdx.x) * 4;
    if      (i < 10485760) cvt4(s0, d0, i);
    else if (i < 20971520) cvt4(s1, d1, i - 10485760);
    else if (i < 23592960) cvt4(s2, d2, i - 20971520);
    else if (i < 26214400) cvt4(s3, d3, i - 23592960);
    else if (i < 36700160) cvt4(s4, d4, i - 26214400);
}

// ---------------- GEMM (256x256, 8-wave, counted vmcnt) for QKV -----------
template<int MH, int NH>
__device__ __forceinline__ void mm16(f32x4 (&acc)[8][4],
                                     const short8 (&a)[4][2],
                                     const short8 (&b)[2][2]) {
#pragma unroll
    for (int k2 = 0; k2 < 2; k2++)
#pragma unroll
        for (int mi = 0; mi < 4; mi++)
#pragma unroll
            for (int nj = 0; nj < 2; nj++)
                acc[MH * 4 + mi][NH * 2 + nj] =
                    MFMA_BF16(a[mi][k2], b[nj][k2], acc[MH * 4 + mi][NH * 2 + nj]);
}

template<bool BF16_OUT>
__global__ __launch_bounds__(512, 2) void gemm8(const u16* __restrict__ A,
                                                const u16* __restrict__ B,
                                                void* __restrict__ Cv,
                                                int K, int lda, int ldb, int ldc,
                                                int ntn)
{
    __shared__ __align__(16) u16 Sm[65536];   // 128 KiB: 2 slots x (A 32KB | B 32KB)
    const int t = threadIdx.x;
    const int w = t >> 6, l = t & 63;
    const int lrow = l & 15, lk = l >> 4;
    const int wm = w >> 2, wn = w & 3;        // 2 x 4 wave grid

    // XCD-chunked block swizzle (grid %8 == 0 guaranteed by launcher)
    const int nwg = (int)gridDim.x;
    const int cpx = nwg >> 3;
    const int id = (int)blockIdx.x;
    const int sw = (id & 7) * cpx + (id >> 3);
    const int tm = sw / ntn, tn = sw - tm * ntn;
    const int m0 = tm * 256, n0 = tn * 256;

    const int nkt = K >> 6;
    const size_t laneOffA = (size_t)(w * 16 + (l >> 3)) * lda + (((l & 7) ^ (l >> 3)) * 8);
    const size_t laneOffB = (size_t)(w * 16 + (l >> 3)) * ldb + (((l & 7) ^ (l >> 3)) * 8);
    const u16* Ag = A + (size_t)m0 * lda;
    const u16* Bg = B + (size_t)n0 * ldb;

    auto STAGE_A = [&](int kt, int slot, int h) {
#pragma unroll
        for (int j = 0; j < 2; j++)
            glds16(Ag + laneOffA + (size_t)(h * 128 + j * 8) * lda + kt * 64,
                   (char*)Sm + slot * 65536 + h * 16384 + w * 2048 + j * 1024);
    };
    auto STAGE_B = [&](int kt, int slot, int h) {
#pragma unroll
        for (int j = 0; j < 2; j++)
            glds16(Bg + laneOffB + (size_t)(h * 128 + j * 8) * ldb + kt * 64,
                   (char*)Sm + 32768 + slot * 65536 + h * 16384 + w * 2048 + j * 1024);
    };
    auto READ_A = [&](short8 (&a)[4][2], int slot, int rb) {
#pragma unroll
        for (int mi = 0; mi < 4; mi++)
#pragma unroll
            for (int k2 = 0; k2 < 2; k2++) {
                int row = rb + mi * 16 + lrow;
                a[mi][k2] = *(const short8*)&Sm[slot * 32768 + row * 64 +
                                                (((k2 * 4 + lk) ^ (lrow & 7)) * 8)];
            }
    };
    auto READ_B = [&](short8 (&b)[2][2], int slot, int rb) {
#pragma unroll
        for (int nj = 0; nj < 2; nj++)
#pragma unroll
            for (int k2 = 0; k2 < 2; k2++) {
                int row = rb + nj * 16 + lrow;
                b[nj][k2] = *(const short8*)&Sm[slot * 32768 + 16384 + row * 64 +
                                                (((k2 * 4 + lk) ^ (lrow & 7)) * 8)];
            }
    };

    f32x4 acc[8][4];
#pragma unroll
    for (int i = 0; i < 8; i++)
#pragma unroll
        for (int j = 0; j < 4; j++) acc[i][j] = (f32x4){0.f, 0.f, 0.f, 0.f};
    short8 aF0[4][2], aF1[4][2], bF0[2][2], bF1[2][2];

    // prologue: K0 fully + K1 A-halves (12 loads/wave); drain to K1.A only
    STAGE_A(0, 0, 0); STAGE_A(0, 0, 1);
    STAGE_B(0, 0, 0); STAGE_B(0, 0, 1);
    const int k1 = (nkt > 1) ? 1 : 0;
    STAGE_A(k1, 1, 0); STAGE_A(k1, 1, 1);
    WAIT_VM(4);
    S_BARRIER();

    for (int kt = 0; kt < nkt; ++kt) {
        const int slot = kt & 1, nslot = slot ^ 1;
        const int ktB = (kt + 1 < nkt) ? kt + 1 : kt;   // clamp keeps vmcnt uniform
        const int ktA = (kt + 2 < nkt) ? kt + 2 : kt;
        // ---- P1
        READ_A(aF0, slot, wm * 128);
        READ_B(bF0, slot, wn * 64);
        STAGE_B(ktB, nslot, 0);
        S_BARRIER();
        WAIT_LGKM0();
        __builtin_amdgcn_sched_barrier(0);
        __builtin_amdgcn_s_setprio(1);
        mm16<0, 0>(acc, aF0, bF0);
        __builtin_amdgcn_s_setprio(0);
        S_BARRIER();
        // ---- P2
        READ_A(aF1, slot, wm * 128 + 64);
        STAGE_B(ktB, nslot, 1);
        S_BARRIER();
        WAIT_LGKM0();
        __builtin_amdgcn_sched_barrier(0);
        __builtin_amdgcn_s_setprio(1);
        mm16<1, 0>(acc, aF1, bF0);
        __builtin_amdgcn_s_setprio(0);
        S_BARRIER();
        // ---- P3
        READ_B(bF1, slot, wn * 64 + 32);
        STAGE_A(ktA, slot, 0);
        S_BARRIER();
        WAIT_LGKM0();
        __builtin_amdgcn_sched_barrier(0);
        __builtin_amdgcn_s_setprio(1);
        mm16<1, 1>(acc, aF1, bF1);
        __builtin_amdgcn_s_setprio(0);
        S_BARRIER();
        // ---- P4
        STAGE_A(ktA, slot, 1);
        S_BARRIER();
        __builtin_amdgcn_s_setprio(1);
        mm16<0, 1>(acc, aF0, bF1);
        __builtin_amdgcn_s_setprio(0);
        WAIT_VM(4);
        S_BARRIER();
    }
    WAIT_VM(0);

    // C/D layout: col = l&15, row = (l>>4)*4 + reg
#pragma unroll
    for (int mi = 0; mi < 8; mi++) {
#pragma unroll
        for (int r = 0; r < 4; r++) {
            int row = m0 + wm * 128 + mi * 16 + lk * 4 + r;
#pragma unroll
            for (int nj = 0; nj < 4; nj++) {
                int col = n0 + wn * 64 + nj * 16 + lrow;
                float v = acc[mi][nj][r];
                if (BF16_OUT) ((u16*)Cv)[(size_t)row * ldc + col] = f2bf(v);
                else          ((float*)Cv)[(size_t)row * ldc + col] = v;
            }
        }
    }
}

// ---------------- GEMM 128x128 (r0 structure) for out-proj ----------------
// 128x128 tile, BK=64, 4 waves each 64x64, 32 KB LDS -> multi-block/CU.
// Used for out-proj (grid 640 blocks fills 256 CUs; 256^2 gives only 160).
template<bool BF16_OUT>
__global__ __launch_bounds__(256) void gemm_bt(const u16* __restrict__ A,
                                               const u16* __restrict__ B,
                                               void* __restrict__ Cv,
                                               int K, int lda, int ldb, int ldc)
{
    __shared__ __align__(16) u16 As[128 * 64];   // 16 KB
    __shared__ __align__(16) u16 Bs[128 * 64];   // 16 KB
    const int t = threadIdx.x;
    const int w = t >> 6, l = t & 63;
    const int m0 = blockIdx.y * 128, n0 = blockIdx.x * 128;
    const int wm = (w & 1) * 64, wn = (w >> 1) * 64;
    const int lrow = l & 15, lk = l >> 4;

    f32x4 acc[4][4];
#pragma unroll
    for (int i = 0; i < 4; i++)
#pragma unroll
        for (int j = 0; j < 4; j++) acc[i][j] = (f32x4){0.f, 0.f, 0.f, 0.f};

    const int row_b = w * 8 + (l >> 3);
    const int gsw = ((l & 7) ^ (l >> 3)) * 8;
    const u16* Ap[4]; const u16* Bp[4];
#pragma unroll
    for (int i = 0; i < 4; i++) {
        Ap[i] = A + (size_t)(m0 + row_b + i * 32) * lda + gsw;
        Bp[i] = B + (size_t)(n0 + row_b + i * 32) * ldb + gsw;
    }
    char* Asb = (char*)As + w * 1024;
    char* Bsb = (char*)Bs + w * 1024;

    for (int k0 = 0; k0 < K; k0 += 64) {
        __syncthreads();
#pragma unroll
        for (int i = 0; i < 4; i++) glds16(Ap[i] + k0, Asb + i * 4096);
#pragma unroll
        for (int i = 0; i < 4; i++) glds16(Bp[i] + k0, Bsb + i * 4096);
        __syncthreads();
#pragma unroll
        for (int k2 = 0; k2 < 2; k2++) {
            const int slb = (k2 * 4 + lk) ^ (lrow & 7);
            short8 af[4], bf[4];
#pragma unroll
            for (int mi = 0; mi < 4; mi++)
                af[mi] = *(const short8*)&As[(wm + mi * 16 + lrow) * 64 + slb * 8];
#pragma unroll
            for (int ni = 0; ni < 4; ni++)
                bf[ni] = *(const short8*)&Bs[(wn + ni * 16 + lrow) * 64 + slb * 8];
#pragma unroll
            for (int mi = 0; mi < 4; mi++)
#pragma unroll
                for (int ni = 0; ni < 4; ni++)
                    acc[mi][ni] = MFMA_BF16(af[mi], bf[ni], acc[mi][ni]);
        }
    }

    // C/D layout: col = l&15, row = (l>>4)*4 + reg
#pragma unroll
    for (int mi = 0; mi < 4; mi++) {
#pragma unroll
        for (int r = 0; r < 4; r++) {
            int row = m0 + wm + mi * 16 + lk * 4 + r;
#pragma unroll
            for (int ni = 0; ni < 4; ni++) {
                int col = n0 + wn + ni * 16 + lrow;
                float v = acc[mi][ni][r];
                if (BF16_OUT) ((u16*)Cv)[(size_t)row * ldc + col] = f2bf(v);
                else          ((float*)Cv)[(size_t)row * ldc + col] = v;
            }
        }
    }
}

// ---------------- RMSNorm + RoPE for Q and K only -------------------------
// One wave per (token, hd); lane l owns d=2l,2l+1; partner via shfl_xor(32).
__global__ __launch_bounds__(256) void norm_rope_qk(const u16* __restrict__ qkv,
        const float* __restrict__ cosb, const float* __restrict__ sinb,
        const float* __restrict__ qg, const float* __restrict__ kg,
        u16* __restrict__ qb, u16* __restrict__ kb, float* __restrict__ k_out)
{
    const int idx = blockIdx.x * 4 + (threadIdx.x >> 6);
    const int l = threadIdx.x & 63;
    const int tok = idx / 40, hd = idx - tok * 40;
    const int b = tok >> 11, pos = tok & 2047;
    const u16* row = qkv + (size_t)tok * 6144 + hd * 128;
    ushort2 xr = *(const ushort2*)(row + 2 * l);
    float xa = bf2f(xr.x), xb = bf2f(xr.y);
    float ss = xa * xa + xb * xb;
#pragma unroll
    for (int m = 1; m < 64; m <<= 1) ss += __shfl_xor(ss, m, 64);
    float rn = rsqrtf(ss * (1.0f / 128.0f) + 1e-6f);

    const float* gm = (hd < 32) ? qg : kg;
    float2 g = *(const float2*)(gm + 2 * l);
    float na = xa * rn * g.x, nb = xb * rn * g.y;
    float pa = __shfl_xor(na, 32, 64);   // partner at d ^ 64
    float pb = __shfl_xor(nb, 32, 64);
    float2 c = *(const float2*)(cosb + (size_t)tok * 128 + 2 * l);
    float2 s = *(const float2*)(sinb + (size_t)tok * 128 + 2 * l);
    float sgn = (l < 32) ? -1.0f : 1.0f;   // rotate_half: -x2 first half, +x1 second
    float ya = na * c.x + sgn * pa * s.x;
    float yb = nb * c.y + sgn * pb * s.y;
    if (hd < 32) {
        const float qs = 0.08838834764831845f;  // 1/sqrt(128) folded into q
        size_t base = (((size_t)b * 32 + hd) * 2048 + pos) * 128;
        ushort2 o; o.x = f2bf(ya * qs); o.y = f2bf(yb * qs);
        *(ushort2*)(qb + base + 2 * l) = o;
    } else {
        int kv = hd - 32;
        size_t base = (((size_t)b * 8 + kv) * 2048 + pos) * 128;
        *(float2*)(k_out + base + 2 * l) = make_float2(ya, yb);
        ushort2 o; o.x = f2bf(ya); o.y = f2bf(yb);
        *(ushort2*)(kb + base + 2 * l) = o;
    }
}

// ---------------- V pack: fp32 new_v (coalesced) + bf16 V^T (LDS transpose)
__global__ __launch_bounds__(256) void v_pack(const u16* __restrict__ qkv,
        float* __restrict__ v_out, u16* __restrict__ vtb)
{
    __shared__ __align__(16) u16 T[64 * 128];   // [pos][d], d-octets XOR (pos&7)
    const int pb = blockIdx.x, bkv = blockIdx.y;
    const int b = bkv >> 3, kv = bkv & 7;
    const int p0 = pb * 64;
    const int t = threadIdx.x;
    const int pos = t >> 2, ch4 = t & 3;
    const u16* src = qkv + (size_t)(b * 2048 + p0 + pos) * 6144 + (40 + kv) * 128 + ch4 * 32;
    float* vdst = v_out + ((size_t)bkv * 2048 + p0 + pos) * 128 + ch4 * 32;
#pragma unroll
    for (int j = 0; j < 4; j++) {
        short8 x = *(const short8*)(src + j * 8);
        float4 f0, f1;
        f0.x = bf2f(x[0]); f0.y = bf2f(x[1]); f0.z = bf2f(x[2]); f0.w = bf2f(x[3]);
        f1.x = bf2f(x[4]); f1.y = bf2f(x[5]); f1.z = bf2f(x[6]); f1.w = bf2f(x[7]);
        *(float4*)(vdst + j * 8)     = f0;
        *(float4*)(vdst + j * 8 + 4) = f1;
        int slot = (ch4 * 4 + j) ^ (pos & 7);
        *(short8*)&T[pos * 128 + slot * 8] = x;
    }
    __syncthreads();
    const int d = t & 127, ph = t >> 7;
    u16* obase = vtb + ((size_t)bkv * 128 + d) * 2048 + p0 + ph * 32;
#pragma unroll
    for (int g = 0; g < 4; g++) {
        short8 tv;
#pragma unroll
        for (int jj = 0; jj < 8; jj++) {
            int pp = ph * 32 + g * 8 + jj;
            int slot = (d >> 3) ^ (pp & 7);
            tv[jj] = (short)T[pp * 128 + slot * 8 + (d & 7)];
        }
        *(short8*)(obase + g * 8) = tv;
    }
}

// ---------------- Flash attention (causal, GQA, static-max softmax) -------
// Round-1 proven structure (2x __syncthreads per tile, __expf) + XCD
// permutation of blockIdx.x: all 4 heads of a kv-group land on the same
// XCD L2 (K/V = 1MB per group, L2-resident) -> the per-tile staging drain
// becomes L2-hit instead of HBM-miss. [r3 verified: FETCH 130->82 MB]
__global__ __launch_bounds__(256, 3) void attn_kernel(const u16* __restrict__ qb,
        const u16* __restrict__ kb, const u16* __restrict__ vtb,
        u16* __restrict__ ao)
{
    __shared__ __align__(16) u16 Ks[64 * 128];    // (kv,d) swizzled, 16KB
    __shared__ __align__(16) u16 Vs[128 * 64];    // (d,kv) swizzled, 16KB
    __shared__ __align__(16) u16 Ps[4][32 * 72];  // per-wave P, stride 72, 18KB

    // dispatch slot p -> bh: kv-group g = (p&7) + (p>>5)*8, head i = (p>>3)&3.
    // Same-group blocks sit at positions == g (mod 8) -> same XCD round-robin.
    const int p = (int)blockIdx.x;
    const int g = (p & 7) + ((p >> 5) << 3);
    const int bh = g * 4 + ((p >> 3) & 3);
    const int b = bh >> 5, h = bh & 31;
    const int kvh = h >> 2;
    const int qt = (int)gridDim.y - 1 - (int)blockIdx.y;   // heavy-first
    const int q0 = qt * 128;
    const int t = threadIdx.x, w = t >> 6, l = t & 63;
    const int lrow = l & 15, lk = l >> 4;

    const u16* qbase  = qb  + ((size_t)b * 32 + h)  * 2048 * 128;
    const u16* kbase  = kb  + ((size_t)b * 8 + kvh) * 2048 * 128;
    const u16* vtbase = vtb + ((size_t)b * 8 + kvh) * 128 * 2048;

    short8 qf[2][4];   // q frags for 2 m-tiles, resident all kernel
#pragma unroll
    for (int m = 0; m < 2; m++) {
        const u16* qrow = qbase + (size_t)(q0 + w * 32 + m * 16 + lrow) * 128 + lk * 8;
#pragma unroll
        for (int ks = 0; ks < 4; ks++) qf[m][ks] = *(const short8*)(qrow + ks * 32);
    }

    f32x4 o[2][8];
#pragma unroll
    for (int m = 0; m < 2; m++)
#pragma unroll
        for (int i = 0; i < 8; i++) o[m][i] = (f32x4){0.f, 0.f, 0.f, 0.f};
    float lsum[2][4] = {{0.f,0.f,0.f,0.f},{0.f,0.f,0.f,0.f}};

    int kR[4], kG[4], vR[4], vG[4];
#pragma unroll
    for (int i = 0; i < 4; i++) {
        int c = i * 256 + t;
        kR[i] = c >> 4; kG[i] = (c & 15) ^ (kR[i] & 7);
        vR[i] = c >> 3; vG[i] = (c & 7)  ^ (vR[i] & 7);
    }
    char* Ksb = (char*)Ks + w * 1024;
    char* Vsb = (char*)Vs + w * 1024;
    u16* pw = &Ps[w][0];
    const int wrow_max = q0 + w * 32 + 31;   // last q row this wave owns

    const int nkt = 2 * qt + 2;
    for (int kt = 0; kt < nkt; kt++) {
        const int kv0 = kt * 64;
        __syncthreads();
#pragma unroll
        for (int i = 0; i < 4; i++)
            glds16(kbase + (size_t)(kv0 + kR[i]) * 128 + kG[i] * 8, Ksb + i * 4096);
#pragma unroll
        for (int i = 0; i < 4; i++)
            glds16(vtbase + (size_t)vR[i] * 2048 + kv0 + vG[i] * 8, Vsb + i * 4096);
        __syncthreads();

        if (kv0 > wrow_max) continue;   // fully masked for this wave

        // S = Q K^T (q pre-scaled by 1/sqrt(D)); kf reused across both m-tiles
        f32x4 s[2][4];
#pragma unroll
        for (int m = 0; m < 2; m++)
#pragma unroll
            for (int i = 0; i < 4; i++) s[m][i] = (f32x4){0.f, 0.f, 0.f, 0.f};
#pragma unroll
        for (int ks = 0; ks < 4; ks++) {
#pragma unroll
            for (int nt = 0; nt < 4; nt++) {
                int r = nt * 16 + lrow;
                int sl = (ks * 4 + lk) ^ (r & 7);
                short8 kf = *(const short8*)&Ks[r * 128 + sl * 8];
                s[0][nt] = MFMA_BF16(qf[0][ks], kf, s[0][nt]);
                s[1][nt] = MFMA_BF16(qf[1][ks], kf, s[1][nt]);
            }
        }

        // causal mask (diagonal-adjacent tiles only), exp, partial row sums, P
#pragma unroll
        for (int m = 0; m < 2; m++) {
            const int rowbase = q0 + w * 32 + m * 16;
            if (kv0 + 63 > rowbase) {
#pragma unroll
                for (int nt = 0; nt < 4; nt++) {
                    int cg = kv0 + nt * 16 + lrow;
#pragma unroll
                    for (int r = 0; r < 4; r++)
                        if (cg > rowbase + lk * 4 + r) s[m][nt][r] = -1e30f;
                }
            }
#pragma unroll
            for (int nt = 0; nt < 4; nt++)
#pragma unroll
                for (int r = 0; r < 4; r++) {
                    float pv = __expf(s[m][nt][r]);   // static max: none needed
                    s[m][nt][r] = pv;
                    lsum[m][r] += pv;
                    pw[(m * 16 + lk * 4 + r) * 72 + nt * 16 + lrow] = f2bf(pv);
                }
        }
        asm volatile("s_waitcnt lgkmcnt(0)" ::: "memory");

        // O += P V ; vf reused across both m-tiles
#pragma unroll
        for (int k2 = 0; k2 < 2; k2++) {
            short8 pf0 = *(const short8*)&pw[lrow * 72 + k2 * 32 + lk * 8];
            short8 pf1 = *(const short8*)&pw[(16 + lrow) * 72 + k2 * 32 + lk * 8];
#pragma unroll
            for (int nt = 0; nt < 8; nt++) {
                int rr = nt * 16 + lrow;
                int sl = (k2 * 4 + lk) ^ (rr & 7);
                short8 vf = *(const short8*)&Vs[rr * 64 + sl * 8];
                o[0][nt] = MFMA_BF16(pf0, vf, o[0][nt]);
                o[1][nt] = MFMA_BF16(pf1, vf, o[1][nt]);
            }
        }
    }

    // one-time cross-lane row-sum reduce (lanes sharing lk hold same rows)
#pragma unroll
    for (int m = 0; m < 2; m++)
#pragma unroll
        for (int r = 0; r < 4; r++) {
            float v = lsum[m][r];
            v += __shfl_xor(v, 1, 64);
            v += __shfl_xor(v, 2, 64);
            v += __shfl_xor(v, 4, 64);
            v += __shfl_xor(v, 8, 64);
            lsum[m][r] = 1.0f / v;
        }
#pragma unroll
    for (int m = 0; m < 2; m++)
#pragma unroll
        for (int nt = 0; nt < 8; nt++)
#pragma unroll
            for (int r = 0; r < 4; r++) {
                int tok = q0 + w * 32 + m * 16 + lk * 4 + r;
                size_t off = ((size_t)b * 2048 + tok) * 4096 + h * 128 + nt * 16 + lrow;
                ao[off] = f2bf(o[m][nt][r] * lsum[m][r]);
            }
}

// ---------------- launcher ----------------
extern "C" void kernel_launch(void* const* d_in, const int* in_sizes, int n_in,
                              void* d_out, int out_size, void* d_ws, size_t ws_size,
                              hipStream_t stream)
{
    (void)in_sizes; (void)n_in; (void)out_size; (void)ws_size;
    const float* hidden = (const float*)d_in[0];
    const float* cosb   = (const float*)d_in[1];
    const float* sinb   = (const float*)d_in[2];
    const float* wq     = (const float*)d_in[3];
    const float* wk     = (const float*)d_in[4];
    const float* wv     = (const float*)d_in[5];
    const float* wo     = (const float*)d_in[6];
    const float* qg     = (const float*)d_in[7];
    const float* kg     = (const float*)d_in[8];

    float* out   = (float*)d_out;                    // (2,2048,2560)
    float* k_out = out + (size_t)2 * 2048 * 2560;    // (2,8,2048,128)
    float* v_out = k_out + (size_t)2 * 8 * 2048 * 128;

    // workspace layout (bf16 elements)
    u16* hid_b = (u16*)d_ws;                  // 4096x2560
    u16* w_b   = hid_b + 10485760;            // 6144x2560 (wq|wk|wv)
    u16* wo_b  = w_b   + 15728640;            // 2560x4096
    u16* q_b   = wo_b  + 10485760;            // (2,32,2048,128)
    u16* k_b   = q_b   + 16777216;            // (2,8,2048,128)
    u16* vt_b  = k_b   + 4194304;             // (2,8,128,2048)
    u16* qkv_b = vt_b  + 4194304;             // 4096x6144
    u16* ao_b  = hid_b;                       // alias: hid_b+w_b dead after QKV

    cvt_all<<<35840, 256, 0, stream>>>(hidden, hid_b, wq, w_b,
                                       wk, w_b + 10485760, wv, w_b + 13107200,
                                       wo, wo_b);

    // QKV: M=4096 tokens, N=6144, K=2560 -> bf16 qkv_b ; grid 16*24=384 (%8==0)
    gemm8<true><<<dim3(384), 512, 0, stream>>>(hid_b, w_b, qkv_b,
                                               2560, 2560, 2560, 6144, 24);
    norm_rope_qk<<<40960, 256, 0, stream>>>(qkv_b, cosb, sinb, qg, kg,
                                            q_b, k_b, k_out);
    v_pack<<<dim3(32, 16), 256, 0, stream>>>(qkv_b, v_out, vt_b);
    attn_kernel<<<dim3(64, 16), 256, 0, stream>>>(q_b, k_b, vt_b, ao_b);
    // out-proj: M=4096, N=2560, K=4096 -> fp32 d_out ; 128^2 tiles, 640 blocks
    gemm_bt<false><<<dim3(20, 32), 256, 0, stream>>>(ao_b, wo_b, out,
                                                     4096, 4096, 4096, 2560);
}

// Round 5
// 602.597 us; speedup vs baseline: 1.0769x; 1.0769x over previous
//
#include <hip/hip_runtime.h>
#include <stdint.h>

typedef unsigned short u16;
typedef __attribute__((ext_vector_type(8))) short short8;
typedef __attribute__((ext_vector_type(4))) float f32x4;

#define MFMA_BF16(a,b,c) __builtin_amdgcn_mfma_f32_16x16x32_bf16((a),(b),(c),0,0,0)

#define S_BARRIER()  asm volatile("s_barrier" ::: "memory")
#define WAIT_LGKM0() asm volatile("s_waitcnt lgkmcnt(0)" ::: "memory")
#define WAIT_VM(N)   asm volatile("s_waitcnt vmcnt(" #N ")" ::: "memory")

__device__ __forceinline__ u16 f2bf(float x) {
    uint32_t u = __builtin_bit_cast(uint32_t, x);
    u += 0x7fffu + ((u >> 16) & 1u);   // RNE
    return (u16)(u >> 16);
}
__device__ __forceinline__ float bf2f(u16 u) {
    return __builtin_bit_cast(float, (uint32_t)u << 16);
}
// async global->LDS, 16B per lane; LDS dest = wave-uniform base + lane*16
__device__ __forceinline__ void glds16(const void* g, void* lds) {
    __builtin_amdgcn_global_load_lds((const __attribute__((address_space(1))) void*)g,
                                     (__attribute__((address_space(3))) void*)lds,
                                     16, 0, 0);
}

// ---------------- fused fp32 -> bf16 convert (all 5 tensors, 1 launch) ----
__device__ __forceinline__ void cvt4(const float* __restrict__ s,
                                     u16* __restrict__ d, int i) {
    float4 v = *(const float4*)(s + i);
    ushort4 o;
    o.x = f2bf(v.x); o.y = f2bf(v.y); o.z = f2bf(v.z); o.w = f2bf(v.w);
    *(ushort4*)(d + i) = o;
}
__global__ __launch_bounds__(256) void cvt_all(
        const float* __restrict__ s0, u16* __restrict__ d0,   // hidden 10485760
        const float* __restrict__ s1, u16* __restrict__ d1,   // wq     10485760
        const float* __restrict__ s2, u16* __restrict__ d2,   // wk      2621440
        const float* __restrict__ s3, u16* __restrict__ d3,   // wv      2621440
        const float* __restrict__ s4, u16* __restrict__ d4)   // wo     10485760
{
    int i = (blockIdx.x * 256 + threadIdx.x) * 4;
    if      (i < 10485760) cvt4(s0, d0, i);
    else if (i < 20971520) cvt4(s1, d1, i - 10485760);
    else if (i < 23592960) cvt4(s2, d2, i - 20971520);
    else if (i < 26214400) cvt4(s3, d3, i - 23592960);
    else if (i < 36700160) cvt4(s4, d4, i - 26214400);
}

// ---------------- GEMM: C[M,N] = A[M,K] * B[N,K]^T (bf16 in, fp32 acc) ----
// 256x256 tile, BK=64, 512 threads = 8 waves (2M x 4N), 128 KiB LDS dbuf.
// 4-phase/K-tile schedule with counted vmcnt (never 0 in loop).
// Used for BOTH QKV (384 blocks) and out-proj (160 blocks): per-block
// efficiency of this structure beats small-tile fill (r4 measured:
// gemm_bt 640-block out-proj = 165us vs gemm8 160-block < 150.5us).
template<int MH, int NH>
__device__ __forceinline__ void mm16(f32x4 (&acc)[8][4],
                                     const short8 (&a)[4][2],
                                     const short8 (&b)[2][2]) {
#pragma unroll
    for (int k2 = 0; k2 < 2; k2++)
#pragma unroll
        for (int mi = 0; mi < 4; mi++)
#pragma unroll
            for (int nj = 0; nj < 2; nj++)
                acc[MH * 4 + mi][NH * 2 + nj] =
                    MFMA_BF16(a[mi][k2], b[nj][k2], acc[MH * 4 + mi][NH * 2 + nj]);
}

template<bool BF16_OUT>
__global__ __launch_bounds__(512, 2) void gemm8(const u16* __restrict__ A,
                                                const u16* __restrict__ B,
                                                void* __restrict__ Cv,
                                                int K, int lda, int ldb, int ldc,
                                                int ntn)
{
    __shared__ __align__(16) u16 Sm[65536];   // 128 KiB: 2 slots x (A 32KB | B 32KB)
    const int t = threadIdx.x;
    const int w = t >> 6, l = t & 63;
    const int lrow = l & 15, lk = l >> 4;
    const int wm = w >> 2, wn = w & 3;        // 2 x 4 wave grid

    // XCD-chunked block swizzle (grid %8 == 0 guaranteed by launcher)
    const int nwg = (int)gridDim.x;
    const int cpx = nwg >> 3;
    const int id = (int)blockIdx.x;
    const int sw = (id & 7) * cpx + (id >> 3);
    const int tm = sw / ntn, tn = sw - tm * ntn;
    const int m0 = tm * 256, n0 = tn * 256;

    const int nkt = K >> 6;
    const size_t laneOffA = (size_t)(w * 16 + (l >> 3)) * lda + (((l & 7) ^ (l >> 3)) * 8);
    const size_t laneOffB = (size_t)(w * 16 + (l >> 3)) * ldb + (((l & 7) ^ (l >> 3)) * 8);
    const u16* Ag = A + (size_t)m0 * lda;
    const u16* Bg = B + (size_t)n0 * ldb;

    auto STAGE_A = [&](int kt, int slot, int h) {
#pragma unroll
        for (int j = 0; j < 2; j++)
            glds16(Ag + laneOffA + (size_t)(h * 128 + j * 8) * lda + kt * 64,
                   (char*)Sm + slot * 65536 + h * 16384 + w * 2048 + j * 1024);
    };
    auto STAGE_B = [&](int kt, int slot, int h) {
#pragma unroll
        for (int j = 0; j < 2; j++)
            glds16(Bg + laneOffB + (size_t)(h * 128 + j * 8) * ldb + kt * 64,
                   (char*)Sm + 32768 + slot * 65536 + h * 16384 + w * 2048 + j * 1024);
    };
    auto READ_A = [&](short8 (&a)[4][2], int slot, int rb) {
#pragma unroll
        for (int mi = 0; mi < 4; mi++)
#pragma unroll
            for (int k2 = 0; k2 < 2; k2++) {
                int row = rb + mi * 16 + lrow;
                a[mi][k2] = *(const short8*)&Sm[slot * 32768 + row * 64 +
                                                (((k2 * 4 + lk) ^ (lrow & 7)) * 8)];
            }
    };
    auto READ_B = [&](short8 (&b)[2][2], int slot, int rb) {
#pragma unroll
        for (int nj = 0; nj < 2; nj++)
#pragma unroll
            for (int k2 = 0; k2 < 2; k2++) {
                int row = rb + nj * 16 + lrow;
                b[nj][k2] = *(const short8*)&Sm[slot * 32768 + 16384 + row * 64 +
                                                (((k2 * 4 + lk) ^ (lrow & 7)) * 8)];
            }
    };

    f32x4 acc[8][4];
#pragma unroll
    for (int i = 0; i < 8; i++)
#pragma unroll
        for (int j = 0; j < 4; j++) acc[i][j] = (f32x4){0.f, 0.f, 0.f, 0.f};
    short8 aF0[4][2], aF1[4][2], bF0[2][2], bF1[2][2];

    // prologue: K0 fully + K1 A-halves (12 loads/wave); drain to K1.A only
    STAGE_A(0, 0, 0); STAGE_A(0, 0, 1);
    STAGE_B(0, 0, 0); STAGE_B(0, 0, 1);
    const int k1 = (nkt > 1) ? 1 : 0;
    STAGE_A(k1, 1, 0); STAGE_A(k1, 1, 1);
    WAIT_VM(4);
    S_BARRIER();

    for (int kt = 0; kt < nkt; ++kt) {
        const int slot = kt & 1, nslot = slot ^ 1;
        const int ktB = (kt + 1 < nkt) ? kt + 1 : kt;   // clamp keeps vmcnt uniform
        const int ktA = (kt + 2 < nkt) ? kt + 2 : kt;
        // ---- P1
        READ_A(aF0, slot, wm * 128);
        READ_B(bF0, slot, wn * 64);
        STAGE_B(ktB, nslot, 0);
        S_BARRIER();
        WAIT_LGKM0();
        __builtin_amdgcn_sched_barrier(0);
        __builtin_amdgcn_s_setprio(1);
        mm16<0, 0>(acc, aF0, bF0);
        __builtin_amdgcn_s_setprio(0);
        S_BARRIER();
        // ---- P2
        READ_A(aF1, slot, wm * 128 + 64);
        STAGE_B(ktB, nslot, 1);
        S_BARRIER();
        WAIT_LGKM0();
        __builtin_amdgcn_sched_barrier(0);
        __builtin_amdgcn_s_setprio(1);
        mm16<1, 0>(acc, aF1, bF0);
        __builtin_amdgcn_s_setprio(0);
        S_BARRIER();
        // ---- P3
        READ_B(bF1, slot, wn * 64 + 32);
        STAGE_A(ktA, slot, 0);
        S_BARRIER();
        WAIT_LGKM0();
        __builtin_amdgcn_sched_barrier(0);
        __builtin_amdgcn_s_setprio(1);
        mm16<1, 1>(acc, aF1, bF1);
        __builtin_amdgcn_s_setprio(0);
        S_BARRIER();
        // ---- P4
        STAGE_A(ktA, slot, 1);
        S_BARRIER();
        __builtin_amdgcn_s_setprio(1);
        mm16<0, 1>(acc, aF0, bF1);
        __builtin_amdgcn_s_setprio(0);
        WAIT_VM(4);
        S_BARRIER();
    }
    WAIT_VM(0);

    // C/D layout: col = l&15, row = (l>>4)*4 + reg
#pragma unroll
    for (int mi = 0; mi < 8; mi++) {
#pragma unroll
        for (int r = 0; r < 4; r++) {
            int row = m0 + wm * 128 + mi * 16 + lk * 4 + r;
#pragma unroll
            for (int nj = 0; nj < 4; nj++) {
                int col = n0 + wn * 64 + nj * 16 + lrow;
                float v = acc[mi][nj][r];
                if (BF16_OUT) ((u16*)Cv)[(size_t)row * ldc + col] = f2bf(v);
                else          ((float*)Cv)[(size_t)row * ldc + col] = v;
            }
        }
    }
}

// ---------------- RMSNorm + RoPE for Q and K only -------------------------
// One wave per (token, hd); lane l owns d=2l,2l+1; partner via shfl_xor(32).
__global__ __launch_bounds__(256) void norm_rope_qk(const u16* __restrict__ qkv,
        const float* __restrict__ cosb, const float* __restrict__ sinb,
        const float* __restrict__ qg, const float* __restrict__ kg,
        u16* __restrict__ qb, u16* __restrict__ kb, float* __restrict__ k_out)
{
    const int idx = blockIdx.x * 4 + (threadIdx.x >> 6);
    const int l = threadIdx.x & 63;
    const int tok = idx / 40, hd = idx - tok * 40;
    const int b = tok >> 11, pos = tok & 2047;
    const u16* row = qkv + (size_t)tok * 6144 + hd * 128;
    ushort2 xr = *(const ushort2*)(row + 2 * l);
    float xa = bf2f(xr.x), xb = bf2f(xr.y);
    float ss = xa * xa + xb * xb;
#pragma unroll
    for (int m = 1; m < 64; m <<= 1) ss += __shfl_xor(ss, m, 64);
    float rn = rsqrtf(ss * (1.0f / 128.0f) + 1e-6f);

    const float* gm = (hd < 32) ? qg : kg;
    float2 g = *(const float2*)(gm + 2 * l);
    float na = xa * rn * g.x, nb = xb * rn * g.y;
    float pa = __shfl_xor(na, 32, 64);   // partner at d ^ 64
    float pb = __shfl_xor(nb, 32, 64);
    float2 c = *(const float2*)(cosb + (size_t)tok * 128 + 2 * l);
    float2 s = *(const float2*)(sinb + (size_t)tok * 128 + 2 * l);
    float sgn = (l < 32) ? -1.0f : 1.0f;   // rotate_half: -x2 first half, +x1 second
    float ya = na * c.x + sgn * pa * s.x;
    float yb = nb * c.y + sgn * pb * s.y;
    if (hd < 32) {
        const float qs = 0.08838834764831845f;  // 1/sqrt(128) folded into q
        size_t base = (((size_t)b * 32 + hd) * 2048 + pos) * 128;
        ushort2 o; o.x = f2bf(ya * qs); o.y = f2bf(yb * qs);
        *(ushort2*)(qb + base + 2 * l) = o;
    } else {
        int kv = hd - 32;
        size_t base = (((size_t)b * 8 + kv) * 2048 + pos) * 128;
        *(float2*)(k_out + base + 2 * l) = make_float2(ya, yb);
        ushort2 o; o.x = f2bf(ya); o.y = f2bf(yb);
        *(ushort2*)(kb + base + 2 * l) = o;
    }
}

// ---------------- V pack: fp32 new_v (coalesced) + bf16 V^T (LDS transpose)
__global__ __launch_bounds__(256) void v_pack(const u16* __restrict__ qkv,
        float* __restrict__ v_out, u16* __restrict__ vtb)
{
    __shared__ __align__(16) u16 T[64 * 128];   // [pos][d], d-octets XOR (pos&7)
    const int pb = blockIdx.x, bkv = blockIdx.y;
    const int b = bkv >> 3, kv = bkv & 7;
    const int p0 = pb * 64;
    const int t = threadIdx.x;
    const int pos = t >> 2, ch4 = t & 3;
    const u16* src = qkv + (size_t)(b * 2048 + p0 + pos) * 6144 + (40 + kv) * 128 + ch4 * 32;
    float* vdst = v_out + ((size_t)bkv * 2048 + p0 + pos) * 128 + ch4 * 32;
#pragma unroll
    for (int j = 0; j < 4; j++) {
        short8 x = *(const short8*)(src + j * 8);
        float4 f0, f1;
        f0.x = bf2f(x[0]); f0.y = bf2f(x[1]); f0.z = bf2f(x[2]); f0.w = bf2f(x[3]);
        f1.x = bf2f(x[4]); f1.y = bf2f(x[5]); f1.z = bf2f(x[6]); f1.w = bf2f(x[7]);
        *(float4*)(vdst + j * 8)     = f0;
        *(float4*)(vdst + j * 8 + 4) = f1;
        int slot = (ch4 * 4 + j) ^ (pos & 7);
        *(short8*)&T[pos * 128 + slot * 8] = x;
    }
    __syncthreads();
    const int d = t & 127, ph = t >> 7;
    u16* obase = vtb + ((size_t)bkv * 128 + d) * 2048 + p0 + ph * 32;
#pragma unroll
    for (int g = 0; g < 4; g++) {
        short8 tv;
#pragma unroll
        for (int jj = 0; jj < 8; jj++) {
            int pp = ph * 32 + g * 8 + jj;
            int slot = (d >> 3) ^ (pp & 7);
            tv[jj] = (short)T[pp * 128 + slot * 8 + (d & 7)];
        }
        *(short8*)(obase + g * 8) = tv;
    }
}

// ---------------- Flash attention (causal, GQA, static-max softmax) -------
// Round-1 proven structure (2x __syncthreads per tile, __expf) + XCD
// permutation of blockIdx.x: all 4 heads of a kv-group land on the same
// XCD L2 (K/V = 1MB per group, L2-resident). [r3/r4 verified: FETCH
// 130 -> 82 -> 48 MB]
__global__ __launch_bounds__(256, 3) void attn_kernel(const u16* __restrict__ qb,
        const u16* __restrict__ kb, const u16* __restrict__ vtb,
        u16* __restrict__ ao)
{
    __shared__ __align__(16) u16 Ks[64 * 128];    // (kv,d) swizzled, 16KB
    __shared__ __align__(16) u16 Vs[128 * 64];    // (d,kv) swizzled, 16KB
    __shared__ __align__(16) u16 Ps[4][32 * 72];  // per-wave P, stride 72, 18KB

    // dispatch slot p -> bh: kv-group g = (p&7) + (p>>5)*8, head i = (p>>3)&3.
    // Same-group blocks sit at positions == g (mod 8) -> same XCD round-robin.
    const int p = (int)blockIdx.x;
    const int g = (p & 7) + ((p >> 5) << 3);
    const int bh = g * 4 + ((p >> 3) & 3);
    const int b = bh >> 5, h = bh & 31;
    const int kvh = h >> 2;
    const int qt = (int)gridDim.y - 1 - (int)blockIdx.y;   // heavy-first
    const int q0 = qt * 128;
    const int t = threadIdx.x, w = t >> 6, l = t & 63;
    const int lrow = l & 15, lk = l >> 4;

    const u16* qbase  = qb  + ((size_t)b * 32 + h)  * 2048 * 128;
    const u16* kbase  = kb  + ((size_t)b * 8 + kvh) * 2048 * 128;
    const u16* vtbase = vtb + ((size_t)b * 8 + kvh) * 128 * 2048;

    short8 qf[2][4];   // q frags for 2 m-tiles, resident all kernel
#pragma unroll
    for (int m = 0; m < 2; m++) {
        const u16* qrow = qbase + (size_t)(q0 + w * 32 + m * 16 + lrow) * 128 + lk * 8;
#pragma unroll
        for (int ks = 0; ks < 4; ks++) qf[m][ks] = *(const short8*)(qrow + ks * 32);
    }

    f32x4 o[2][8];
#pragma unroll
    for (int m = 0; m < 2; m++)
#pragma unroll
        for (int i = 0; i < 8; i++) o[m][i] = (f32x4){0.f, 0.f, 0.f, 0.f};
    float lsum[2][4] = {{0.f,0.f,0.f,0.f},{0.f,0.f,0.f,0.f}};

    int kR[4], kG[4], vR[4], vG[4];
#pragma unroll
    for (int i = 0; i < 4; i++) {
        int c = i * 256 + t;
        kR[i] = c >> 4; kG[i] = (c & 15) ^ (kR[i] & 7);
        vR[i] = c >> 3; vG[i] = (c & 7)  ^ (vR[i] & 7);
    }
    char* Ksb = (char*)Ks + w * 1024;
    char* Vsb = (char*)Vs + w * 1024;
    u16* pw = &Ps[w][0];
    const int wrow_max = q0 + w * 32 + 31;   // last q row this wave owns

    const int nkt = 2 * qt + 2;
    for (int kt = 0; kt < nkt; kt++) {
        const int kv0 = kt * 64;
        __syncthreads();
#pragma unroll
        for (int i = 0; i < 4; i++)
            glds16(kbase + (size_t)(kv0 + kR[i]) * 128 + kG[i] * 8, Ksb + i * 4096);
#pragma unroll
        for (int i = 0; i < 4; i++)
            glds16(vtbase + (size_t)vR[i] * 2048 + kv0 + vG[i] * 8, Vsb + i * 4096);
        __syncthreads();

        if (kv0 > wrow_max) continue;   // fully masked for this wave

        // S = Q K^T (q pre-scaled by 1/sqrt(D)); kf reused across both m-tiles
        f32x4 s[2][4];
#pragma unroll
        for (int m = 0; m < 2; m++)
#pragma unroll
            for (int i = 0; i < 4; i++) s[m][i] = (f32x4){0.f, 0.f, 0.f, 0.f};
#pragma unroll
        for (int ks = 0; ks < 4; ks++) {
#pragma unroll
            for (int nt = 0; nt < 4; nt++) {
                int r = nt * 16 + lrow;
                int sl = (ks * 4 + lk) ^ (r & 7);
                short8 kf = *(const short8*)&Ks[r * 128 + sl * 8];
                s[0][nt] = MFMA_BF16(qf[0][ks], kf, s[0][nt]);
                s[1][nt] = MFMA_BF16(qf[1][ks], kf, s[1][nt]);
            }
        }

        // causal mask (diagonal-adjacent tiles only), exp, partial row sums, P
#pragma unroll
        for (int m = 0; m < 2; m++) {
            const int rowbase = q0 + w * 32 + m * 16;
            if (kv0 + 63 > rowbase) {
#pragma unroll
                for (int nt = 0; nt < 4; nt++) {
                    int cg = kv0 + nt * 16 + lrow;
#pragma unroll
                    for (int r = 0; r < 4; r++)
                        if (cg > rowbase + lk * 4 + r) s[m][nt][r] = -1e30f;
                }
            }
#pragma unroll
            for (int nt = 0; nt < 4; nt++)
#pragma unroll
                for (int r = 0; r < 4; r++) {
                    float pv = __expf(s[m][nt][r]);   // static max: none needed
                    s[m][nt][r] = pv;
                    lsum[m][r] += pv;
                    pw[(m * 16 + lk * 4 + r) * 72 + nt * 16 + lrow] = f2bf(pv);
                }
        }
        asm volatile("s_waitcnt lgkmcnt(0)" ::: "memory");

        // O += P V ; vf reused across both m-tiles
#pragma unroll
        for (int k2 = 0; k2 < 2; k2++) {
            short8 pf0 = *(const short8*)&pw[lrow * 72 + k2 * 32 + lk * 8];
            short8 pf1 = *(const short8*)&pw[(16 + lrow) * 72 + k2 * 32 + lk * 8];
#pragma unroll
            for (int nt = 0; nt < 8; nt++) {
                int rr = nt * 16 + lrow;
                int sl = (k2 * 4 + lk) ^ (rr & 7);
                short8 vf = *(const short8*)&Vs[rr * 64 + sl * 8];
                o[0][nt] = MFMA_BF16(pf0, vf, o[0][nt]);
                o[1][nt] = MFMA_BF16(pf1, vf, o[1][nt]);
            }
        }
    }

    // one-time cross-lane row-sum reduce (lanes sharing lk hold same rows)
#pragma unroll
    for (int m = 0; m < 2; m++)
#pragma unroll
        for (int r = 0; r < 4; r++) {
            float v = lsum[m][r];
            v += __shfl_xor(v, 1, 64);
            v += __shfl_xor(v, 2, 64);
            v += __shfl_xor(v, 4, 64);
            v += __shfl_xor(v, 8, 64);
            lsum[m][r] = 1.0f / v;
        }
#pragma unroll
    for (int m = 0; m < 2; m++)
#pragma unroll
        for (int nt = 0; nt < 8; nt++)
#pragma unroll
            for (int r = 0; r < 4; r++) {
                int tok = q0 + w * 32 + m * 16 + lk * 4 + r;
                size_t off = ((size_t)b * 2048 + tok) * 4096 + h * 128 + nt * 16 + lrow;
                ao[off] = f2bf(o[m][nt][r] * lsum[m][r]);
            }
}

// ---------------- launcher ----------------
extern "C" void kernel_launch(void* const* d_in, const int* in_sizes, int n_in,
                              void* d_out, int out_size, void* d_ws, size_t ws_size,
                              hipStream_t stream)
{
    (void)in_sizes; (void)n_in; (void)out_size; (void)ws_size;
    const float* hidden = (const float*)d_in[0];
    const float* cosb   = (const float*)d_in[1];
    const float* sinb   = (const float*)d_in[2];
    const float* wq     = (const float*)d_in[3];
    const float* wk     = (const float*)d_in[4];
    const float* wv     = (const float*)d_in[5];
    const float* wo     = (const float*)d_in[6];
    const float* qg     = (const float*)d_in[7];
    const float* kg     = (const float*)d_in[8];

    float* out   = (float*)d_out;                    // (2,2048,2560)
    float* k_out = out + (size_t)2 * 2048 * 2560;    // (2,8,2048,128)
    float* v_out = k_out + (size_t)2 * 8 * 2048 * 128;

    // workspace layout (bf16 elements)
    u16* hid_b = (u16*)d_ws;                  // 4096x2560
    u16* w_b   = hid_b + 10485760;            // 6144x2560 (wq|wk|wv)
    u16* wo_b  = w_b   + 15728640;            // 2560x4096
    u16* q_b   = wo_b  + 10485760;            // (2,32,2048,128)
    u16* k_b   = q_b   + 16777216;            // (2,8,2048,128)
    u16* vt_b  = k_b   + 4194304;             // (2,8,128,2048)
    u16* qkv_b = vt_b  + 4194304;             // 4096x6144
    u16* ao_b  = hid_b;                       // alias: hid_b+w_b dead after QKV

    cvt_all<<<35840, 256, 0, stream>>>(hidden, hid_b, wq, w_b,
                                       wk, w_b + 10485760, wv, w_b + 13107200,
                                       wo, wo_b);

    // QKV: M=4096 tokens, N=6144, K=2560 -> bf16 qkv_b ; grid 16*24=384 (%8==0)
    gemm8<true><<<dim3(384), 512, 0, stream>>>(hid_b, w_b, qkv_b,
                                               2560, 2560, 2560, 6144, 24);
    norm_rope_qk<<<40960, 256, 0, stream>>>(qkv_b, cosb, sinb, qg, kg,
                                            q_b, k_b, k_out);
    v_pack<<<dim3(32, 16), 256, 0, stream>>>(qkv_b, v_out, vt_b);
    attn_kernel<<<dim3(64, 16), 256, 0, stream>>>(q_b, k_b, vt_b, ao_b);
    // out-proj: M=4096, N=2560, K=4096 -> fp32 d_out ; grid 16*10=160 (%8==0)
    gemm8<false><<<dim3(160), 512, 0, stream>>>(ao_b, wo_b, out,
                                                4096, 4096, 4096, 2560, 10);
}

// Round 6
// 598.053 us; speedup vs baseline: 1.0851x; 1.0076x over previous
//
#include <hip/hip_runtime.h>
#include <stdint.h>

typedef unsigned short u16;
typedef __attribute__((ext_vector_type(8))) short short8;
typedef __attribute__((ext_vector_type(4))) float f32x4;

#define MFMA_BF16(a,b,c) __builtin_amdgcn_mfma_f32_16x16x32_bf16((a),(b),(c),0,0,0)

#define S_BARRIER()  asm volatile("s_barrier" ::: "memory")
#define WAIT_LGKM0() asm volatile("s_waitcnt lgkmcnt(0)" ::: "memory")
#define WAIT_VM(N)   asm volatile("s_waitcnt vmcnt(" #N ")" ::: "memory")

__device__ __forceinline__ u16 f2bf(float x) {
    uint32_t u = __builtin_bit_cast(uint32_t, x);
    u += 0x7fffu + ((u >> 16) & 1u);   // RNE
    return (u16)(u >> 16);
}
__device__ __forceinline__ float bf2f(u16 u) {
    return __builtin_bit_cast(float, (uint32_t)u << 16);
}
// async global->LDS, 16B per lane; LDS dest = wave-uniform base + lane*16
__device__ __forceinline__ void glds16(const void* g, void* lds) {
    __builtin_amdgcn_global_load_lds((const __attribute__((address_space(1))) void*)g,
                                     (__attribute__((address_space(3))) void*)lds,
                                     16, 0, 0);
}

// ---------------- fused fp32 -> bf16 convert (all 5 tensors, 1 launch) ----
__device__ __forceinline__ void cvt4(const float* __restrict__ s,
                                     u16* __restrict__ d, int i) {
    float4 v = *(const float4*)(s + i);
    ushort4 o;
    o.x = f2bf(v.x); o.y = f2bf(v.y); o.z = f2bf(v.z); o.w = f2bf(v.w);
    *(ushort4*)(d + i) = o;
}
__global__ __launch_bounds__(256) void cvt_all(
        const float* __restrict__ s0, u16* __restrict__ d0,   // hidden 10485760
        const float* __restrict__ s1, u16* __restrict__ d1,   // wq     10485760
        const float* __restrict__ s2, u16* __restrict__ d2,   // wk      2621440
        const float* __restrict__ s3, u16* __restrict__ d3,   // wv      2621440
        const float* __restrict__ s4, u16* __restrict__ d4)   // wo     10485760
{
    int i = (blockIdx.x * 256 + threadIdx.x) * 4;
    if      (i < 10485760) cvt4(s0, d0, i);
    else if (i < 20971520) cvt4(s1, d1, i - 10485760);
    else if (i < 23592960) cvt4(s2, d2, i - 20971520);
    else if (i < 26214400) cvt4(s3, d3, i - 23592960);
    else if (i < 36700160) cvt4(s4, d4, i - 26214400);
}

// ---------------- GEMM 256x256 (8-wave, counted vmcnt) for out-proj -------
template<int MH, int NH>
__device__ __forceinline__ void mm16(f32x4 (&acc)[8][4],
                                     const short8 (&a)[4][2],
                                     const short8 (&b)[2][2]) {
#pragma unroll
    for (int k2 = 0; k2 < 2; k2++)
#pragma unroll
        for (int mi = 0; mi < 4; mi++)
#pragma unroll
            for (int nj = 0; nj < 2; nj++)
                acc[MH * 4 + mi][NH * 2 + nj] =
                    MFMA_BF16(a[mi][k2], b[nj][k2], acc[MH * 4 + mi][NH * 2 + nj]);
}

template<bool BF16_OUT>
__global__ __launch_bounds__(512, 2) void gemm8(const u16* __restrict__ A,
                                                const u16* __restrict__ B,
                                                void* __restrict__ Cv,
                                                int K, int lda, int ldb, int ldc,
                                                int ntn)
{
    __shared__ __align__(16) u16 Sm[65536];   // 128 KiB: 2 slots x (A 32KB | B 32KB)
    const int t = threadIdx.x;
    const int w = t >> 6, l = t & 63;
    const int lrow = l & 15, lk = l >> 4;
    const int wm = w >> 2, wn = w & 3;        // 2 x 4 wave grid

    const int nwg = (int)gridDim.x;
    const int cpx = nwg >> 3;
    const int id = (int)blockIdx.x;
    const int sw = (id & 7) * cpx + (id >> 3);
    const int tm = sw / ntn, tn = sw - tm * ntn;
    const int m0 = tm * 256, n0 = tn * 256;

    const int nkt = K >> 6;
    const size_t laneOffA = (size_t)(w * 16 + (l >> 3)) * lda + (((l & 7) ^ (l >> 3)) * 8);
    const size_t laneOffB = (size_t)(w * 16 + (l >> 3)) * ldb + (((l & 7) ^ (l >> 3)) * 8);
    const u16* Ag = A + (size_t)m0 * lda;
    const u16* Bg = B + (size_t)n0 * ldb;

    auto STAGE_A = [&](int kt, int slot, int h) {
#pragma unroll
        for (int j = 0; j < 2; j++)
            glds16(Ag + laneOffA + (size_t)(h * 128 + j * 8) * lda + kt * 64,
                   (char*)Sm + slot * 65536 + h * 16384 + w * 2048 + j * 1024);
    };
    auto STAGE_B = [&](int kt, int slot, int h) {
#pragma unroll
        for (int j = 0; j < 2; j++)
            glds16(Bg + laneOffB + (size_t)(h * 128 + j * 8) * ldb + kt * 64,
                   (char*)Sm + 32768 + slot * 65536 + h * 16384 + w * 2048 + j * 1024);
    };
    auto READ_A = [&](short8 (&a)[4][2], int slot, int rb) {
#pragma unroll
        for (int mi = 0; mi < 4; mi++)
#pragma unroll
            for (int k2 = 0; k2 < 2; k2++) {
                int row = rb + mi * 16 + lrow;
                a[mi][k2] = *(const short8*)&Sm[slot * 32768 + row * 64 +
                                                (((k2 * 4 + lk) ^ (lrow & 7)) * 8)];
            }
    };
    auto READ_B = [&](short8 (&b)[2][2], int slot, int rb) {
#pragma unroll
        for (int nj = 0; nj < 2; nj++)
#pragma unroll
            for (int k2 = 0; k2 < 2; k2++) {
                int row = rb + nj * 16 + lrow;
                b[nj][k2] = *(const short8*)&Sm[slot * 32768 + 16384 + row * 64 +
                                                (((k2 * 4 + lk) ^ (lrow & 7)) * 8)];
            }
    };

    f32x4 acc[8][4];
#pragma unroll
    for (int i = 0; i < 8; i++)
#pragma unroll
        for (int j = 0; j < 4; j++) acc[i][j] = (f32x4){0.f, 0.f, 0.f, 0.f};
    short8 aF0[4][2], aF1[4][2], bF0[2][2], bF1[2][2];

    STAGE_A(0, 0, 0); STAGE_A(0, 0, 1);
    STAGE_B(0, 0, 0); STAGE_B(0, 0, 1);
    const int k1 = (nkt > 1) ? 1 : 0;
    STAGE_A(k1, 1, 0); STAGE_A(k1, 1, 1);
    WAIT_VM(4);
    S_BARRIER();

    for (int kt = 0; kt < nkt; ++kt) {
        const int slot = kt & 1, nslot = slot ^ 1;
        const int ktB = (kt + 1 < nkt) ? kt + 1 : kt;
        const int ktA = (kt + 2 < nkt) ? kt + 2 : kt;
        // ---- P1
        READ_A(aF0, slot, wm * 128);
        READ_B(bF0, slot, wn * 64);
        STAGE_B(ktB, nslot, 0);
        S_BARRIER();
        WAIT_LGKM0();
        __builtin_amdgcn_sched_barrier(0);
        __builtin_amdgcn_s_setprio(1);
        mm16<0, 0>(acc, aF0, bF0);
        __builtin_amdgcn_s_setprio(0);
        S_BARRIER();
        // ---- P2
        READ_A(aF1, slot, wm * 128 + 64);
        STAGE_B(ktB, nslot, 1);
        S_BARRIER();
        WAIT_LGKM0();
        __builtin_amdgcn_sched_barrier(0);
        __builtin_amdgcn_s_setprio(1);
        mm16<1, 0>(acc, aF1, bF0);
        __builtin_amdgcn_s_setprio(0);
        S_BARRIER();
        // ---- P3
        READ_B(bF1, slot, wn * 64 + 32);
        STAGE_A(ktA, slot, 0);
        S_BARRIER();
        WAIT_LGKM0();
        __builtin_amdgcn_sched_barrier(0);
        __builtin_amdgcn_s_setprio(1);
        mm16<1, 1>(acc, aF1, bF1);
        __builtin_amdgcn_s_setprio(0);
        S_BARRIER();
        // ---- P4
        STAGE_A(ktA, slot, 1);
        S_BARRIER();
        __builtin_amdgcn_s_setprio(1);
        mm16<0, 1>(acc, aF0, bF1);
        __builtin_amdgcn_s_setprio(0);
        WAIT_VM(4);
        S_BARRIER();
    }
    WAIT_VM(0);

#pragma unroll
    for (int mi = 0; mi < 8; mi++) {
#pragma unroll
        for (int r = 0; r < 4; r++) {
            int row = m0 + wm * 128 + mi * 16 + lk * 4 + r;
#pragma unroll
            for (int nj = 0; nj < 4; nj++) {
                int col = n0 + wn * 64 + nj * 16 + lrow;
                float v = acc[mi][nj][r];
                if (BF16_OUT) ((u16*)Cv)[(size_t)row * ldc + col] = f2bf(v);
                else          ((float*)Cv)[(size_t)row * ldc + col] = v;
            }
        }
    }
}

// ---------------- GEMM 256x192 (8-wave, counted vmcnt) for QKV ------------
// Same 4-phase ledger as gemm8; B tile = 192 rows staged as 3x64-row calls
// (P1:1, P2:2, P3:2A, P4:2A -> 7 calls/K-tile; WAIT_VM(4) at P4-end leaves
// exactly the 4 A(kt+2) calls in flight). Grid 16x32 = 512 = 2 FULL rounds
// of 256 CUs (vs 256^2's 384 = 1.5 rounds with half-empty tail).
__global__ __launch_bounds__(512, 2) void gemm192(const u16* __restrict__ A,
                                                  const u16* __restrict__ B,
                                                  u16* __restrict__ C,
                                                  int K, int lda, int ldb, int ldc)
{
    __shared__ __align__(16) u16 Sm[57344];   // 112 KiB: A 2x32KB | B 2x24KB
    const int t = threadIdx.x;
    const int w = t >> 6, l = t & 63;
    const int lrow = l & 15, lk = l >> 4;
    const int wm = w >> 2, wn = w & 3;        // 2M x 4N wave grid, wave = 128x48

    const int nwg = (int)gridDim.x;           // 512, %8==0
    const int cpx = nwg >> 3;
    const int id = (int)blockIdx.x;
    const int sw = (id & 7) * cpx + (id >> 3);
    const int tm = sw >> 5, tn = sw & 31;     // 16 x 32 tiles
    const int m0 = tm * 256, n0 = tn * 192;

    const int nkt = K >> 6;
    const size_t laneOffA = (size_t)(w * 16 + (l >> 3)) * lda + (((l & 7) ^ (l >> 3)) * 8);
    const size_t laneOffB = (size_t)(w * 24 + (l >> 3)) * ldb + (((l & 7) ^ (l >> 3)) * 8);
    const u16* Ag = A + (size_t)m0 * lda;
    const u16* Bg = B + (size_t)n0 * ldb;

    auto STAGE_A = [&](int kt, int slot, int h) {
#pragma unroll
        for (int j = 0; j < 2; j++)
            glds16(Ag + laneOffA + (size_t)(h * 128 + j * 8) * lda + kt * 64,
                   (char*)Sm + slot * 32768 + h * 16384 + w * 2048 + j * 1024);
    };
    // one call = 64 rows (8/wave); b in {0,1,2}
    auto STAGE_B1 = [&](int kt, int slot, int b) {
        glds16(Bg + laneOffB + (size_t)(b * 8) * ldb + kt * 64,
               (char*)Sm + 65536 + slot * 24576 + w * 3072 + b * 1024);
    };
    auto READ_A = [&](short8 (&a)[4][2], int slot, int rb) {
#pragma unroll
        for (int mi = 0; mi < 4; mi++)
#pragma unroll
            for (int k2 = 0; k2 < 2; k2++) {
                int row = rb + mi * 16 + lrow;
                a[mi][k2] = *(const short8*)&Sm[slot * 16384 + row * 64 +
                                                (((k2 * 4 + lk) ^ (lrow & 7)) * 8)];
            }
    };
    auto READ_B2 = [&](short8 (&b)[2][2], int slot) {      // frags 0,1
#pragma unroll
        for (int nj = 0; nj < 2; nj++)
#pragma unroll
            for (int k2 = 0; k2 < 2; k2++) {
                int row = wn * 48 + nj * 16 + lrow;
                b[nj][k2] = *(const short8*)&Sm[32768 + slot * 12288 + row * 64 +
                                                (((k2 * 4 + lk) ^ (lrow & 7)) * 8)];
            }
    };
    auto READ_B1 = [&](short8 (&b)[1][2], int slot) {      // frag 2
#pragma unroll
        for (int k2 = 0; k2 < 2; k2++) {
            int row = wn * 48 + 32 + lrow;
            b[0][k2] = *(const short8*)&Sm[32768 + slot * 12288 + row * 64 +
                                           (((k2 * 4 + lk) ^ (lrow & 7)) * 8)];
        }
    };

    f32x4 acc[8][3];
#pragma unroll
    for (int i = 0; i < 8; i++)
#pragma unroll
        for (int j = 0; j < 3; j++) acc[i][j] = (f32x4){0.f, 0.f, 0.f, 0.f};
    short8 aF0[4][2], aF1[4][2], bF0[2][2], bF1[1][2];

    // prologue: K0 full (A 4 + B 3) + K1 A-halves (4); drain to K1.A only
    STAGE_A(0, 0, 0); STAGE_A(0, 0, 1);
    STAGE_B1(0, 0, 0); STAGE_B1(0, 0, 1); STAGE_B1(0, 0, 2);
    const int k1 = (nkt > 1) ? 1 : 0;
    STAGE_A(k1, 1, 0); STAGE_A(k1, 1, 1);
    WAIT_VM(4);
    S_BARRIER();

    for (int kt = 0; kt < nkt; ++kt) {
        const int slot = kt & 1, nslot = slot ^ 1;
        const int ktB = (kt + 1 < nkt) ? kt + 1 : kt;
        const int ktA = (kt + 2 < nkt) ? kt + 2 : kt;
        // ---- P1: read A.lo + B.frags01; stage B0(kt+1)
        READ_A(aF0, slot, wm * 128);
        READ_B2(bF0, slot);
        STAGE_B1(ktB, nslot, 0);
        S_BARRIER();
        WAIT_LGKM0();
        __builtin_amdgcn_sched_barrier(0);
        __builtin_amdgcn_s_setprio(1);
#pragma unroll
        for (int k2 = 0; k2 < 2; k2++)
#pragma unroll
            for (int mi = 0; mi < 4; mi++)
#pragma unroll
                for (int nj = 0; nj < 2; nj++)
                    acc[mi][nj] = MFMA_BF16(aF0[mi][k2], bF0[nj][k2], acc[mi][nj]);
        __builtin_amdgcn_s_setprio(0);
        S_BARRIER();
        // ---- P2: read A.hi; stage B1,B2(kt+1)
        READ_A(aF1, slot, wm * 128 + 64);
        STAGE_B1(ktB, nslot, 1); STAGE_B1(ktB, nslot, 2);
        S_BARRIER();
        WAIT_LGKM0();
        __builtin_amdgcn_sched_barrier(0);
        __builtin_amdgcn_s_setprio(1);
#pragma unroll
        for (int k2 = 0; k2 < 2; k2++)
#pragma unroll
            for (int mi = 0; mi < 4; mi++)
#pragma unroll
                for (int nj = 0; nj < 2; nj++)
                    acc[4 + mi][nj] = MFMA_BF16(aF1[mi][k2], bF0[nj][k2], acc[4 + mi][nj]);
        __builtin_amdgcn_s_setprio(0);
        S_BARRIER();
        // ---- P3: read B.frag2; stage A0(kt+2)
        READ_B1(bF1, slot);
        STAGE_A(ktA, slot, 0);
        S_BARRIER();
        WAIT_LGKM0();
        __builtin_amdgcn_sched_barrier(0);
        __builtin_amdgcn_s_setprio(1);
#pragma unroll
        for (int k2 = 0; k2 < 2; k2++)
#pragma unroll
            for (int mi = 0; mi < 4; mi++)
                acc[4 + mi][2] = MFMA_BF16(aF1[mi][k2], bF1[0][k2], acc[4 + mi][2]);
        __builtin_amdgcn_s_setprio(0);
        S_BARRIER();
        // ---- P4: stage A1(kt+2); counted vmcnt (never 0)
        STAGE_A(ktA, slot, 1);
        S_BARRIER();
        __builtin_amdgcn_s_setprio(1);
#pragma unroll
        for (int k2 = 0; k2 < 2; k2++)
#pragma unroll
            for (int mi = 0; mi < 4; mi++)
                acc[mi][2] = MFMA_BF16(aF0[mi][k2], bF1[0][k2], acc[mi][2]);
        __builtin_amdgcn_s_setprio(0);
        WAIT_VM(4);
        S_BARRIER();
    }
    WAIT_VM(0);

    // C/D layout: col = l&15, row = (l>>4)*4 + reg
#pragma unroll
    for (int mi = 0; mi < 8; mi++) {
#pragma unroll
        for (int r = 0; r < 4; r++) {
            int row = m0 + wm * 128 + mi * 16 + lk * 4 + r;
#pragma unroll
            for (int nj = 0; nj < 3; nj++) {
                int col = n0 + wn * 48 + nj * 16 + lrow;
                C[(size_t)row * ldc + col] = f2bf(acc[mi][nj][r]);
            }
        }
    }
}

// ---------------- RMSNorm + RoPE for Q and K only -------------------------
__global__ __launch_bounds__(256) void norm_rope_qk(const u16* __restrict__ qkv,
        const float* __restrict__ cosb, const float* __restrict__ sinb,
        const float* __restrict__ qg, const float* __restrict__ kg,
        u16* __restrict__ qb, u16* __restrict__ kb, float* __restrict__ k_out)
{
    const int idx = blockIdx.x * 4 + (threadIdx.x >> 6);
    const int l = threadIdx.x & 63;
    const int tok = idx / 40, hd = idx - tok * 40;
    const int b = tok >> 11, pos = tok & 2047;
    const u16* row = qkv + (size_t)tok * 6144 + hd * 128;
    ushort2 xr = *(const ushort2*)(row + 2 * l);
    float xa = bf2f(xr.x), xb = bf2f(xr.y);
    float ss = xa * xa + xb * xb;
#pragma unroll
    for (int m = 1; m < 64; m <<= 1) ss += __shfl_xor(ss, m, 64);
    float rn = rsqrtf(ss * (1.0f / 128.0f) + 1e-6f);

    const float* gm = (hd < 32) ? qg : kg;
    float2 g = *(const float2*)(gm + 2 * l);
    float na = xa * rn * g.x, nb = xb * rn * g.y;
    float pa = __shfl_xor(na, 32, 64);   // partner at d ^ 64
    float pb = __shfl_xor(nb, 32, 64);
    float2 c = *(const float2*)(cosb + (size_t)tok * 128 + 2 * l);
    float2 s = *(const float2*)(sinb + (size_t)tok * 128 + 2 * l);
    float sgn = (l < 32) ? -1.0f : 1.0f;   // rotate_half
    float ya = na * c.x + sgn * pa * s.x;
    float yb = nb * c.y + sgn * pb * s.y;
    if (hd < 32) {
        const float qs = 0.08838834764831845f;  // 1/sqrt(128) folded into q
        size_t base = (((size_t)b * 32 + hd) * 2048 + pos) * 128;
        ushort2 o; o.x = f2bf(ya * qs); o.y = f2bf(yb * qs);
        *(ushort2*)(qb + base + 2 * l) = o;
    } else {
        int kv = hd - 32;
        size_t base = (((size_t)b * 8 + kv) * 2048 + pos) * 128;
        *(float2*)(k_out + base + 2 * l) = make_float2(ya, yb);
        ushort2 o; o.x = f2bf(ya); o.y = f2bf(yb);
        *(ushort2*)(kb + base + 2 * l) = o;
    }
}

// ---------------- V pack: fp32 new_v (coalesced) + bf16 V^T (LDS transpose)
__global__ __launch_bounds__(256) void v_pack(const u16* __restrict__ qkv,
        float* __restrict__ v_out, u16* __restrict__ vtb)
{
    __shared__ __align__(16) u16 T[64 * 128];   // [pos][d], d-octets XOR (pos&7)
    const int pb = blockIdx.x, bkv = blockIdx.y;
    const int b = bkv >> 3, kv = bkv & 7;
    const int p0 = pb * 64;
    const int t = threadIdx.x;
    const int pos = t >> 2, ch4 = t & 3;
    const u16* src = qkv + (size_t)(b * 2048 + p0 + pos) * 6144 + (40 + kv) * 128 + ch4 * 32;
    float* vdst = v_out + ((size_t)bkv * 2048 + p0 + pos) * 128 + ch4 * 32;
#pragma unroll
    for (int j = 0; j < 4; j++) {
        short8 x = *(const short8*)(src + j * 8);
        float4 f0, f1;
        f0.x = bf2f(x[0]); f0.y = bf2f(x[1]); f0.z = bf2f(x[2]); f0.w = bf2f(x[3]);
        f1.x = bf2f(x[4]); f1.y = bf2f(x[5]); f1.z = bf2f(x[6]); f1.w = bf2f(x[7]);
        *(float4*)(vdst + j * 8)     = f0;
        *(float4*)(vdst + j * 8 + 4) = f1;
        int slot = (ch4 * 4 + j) ^ (pos & 7);
        *(short8*)&T[pos * 128 + slot * 8] = x;
    }
    __syncthreads();
    const int d = t & 127, ph = t >> 7;
    u16* obase = vtb + ((size_t)bkv * 128 + d) * 2048 + p0 + ph * 32;
#pragma unroll
    for (int g = 0; g < 4; g++) {
        short8 tv;
#pragma unroll
        for (int jj = 0; jj < 8; jj++) {
            int pp = ph * 32 + g * 8 + jj;
            int slot = (d >> 3) ^ (pp & 7);
            tv[jj] = (short)T[pp * 128 + slot * 8 + (d & 7)];
        }
        *(short8*)(obase + g * 8) = tv;
    }
}

// ---------------- Flash attention (causal, GQA, static-max softmax) -------
// Round-1 proven structure + XCD permutation (FETCH 130->48 MB verified)
// + s_setprio(1) around MFMA clusters (T5; attn runs 3 blocks/CU at
// independent phases -> scheduler has roles to arbitrate, m191 +4-7%).
__global__ __launch_bounds__(256, 3) void attn_kernel(const u16* __restrict__ qb,
        const u16* __restrict__ kb, const u16* __restrict__ vtb,
        u16* __restrict__ ao)
{
    __shared__ __align__(16) u16 Ks[64 * 128];    // (kv,d) swizzled, 16KB
    __shared__ __align__(16) u16 Vs[128 * 64];    // (d,kv) swizzled, 16KB
    __shared__ __align__(16) u16 Ps[4][32 * 72];  // per-wave P, stride 72, 18KB

    const int p = (int)blockIdx.x;
    const int g = (p & 7) + ((p >> 5) << 3);
    const int bh = g * 4 + ((p >> 3) & 3);
    const int b = bh >> 5, h = bh & 31;
    const int kvh = h >> 2;
    const int qt = (int)gridDim.y - 1 - (int)blockIdx.y;   // heavy-first
    const int q0 = qt * 128;
    const int t = threadIdx.x, w = t >> 6, l = t & 63;
    const int lrow = l & 15, lk = l >> 4;

    const u16* qbase  = qb  + ((size_t)b * 32 + h)  * 2048 * 128;
    const u16* kbase  = kb  + ((size_t)b * 8 + kvh) * 2048 * 128;
    const u16* vtbase = vtb + ((size_t)b * 8 + kvh) * 128 * 2048;

    short8 qf[2][4];
#pragma unroll
    for (int m = 0; m < 2; m++) {
        const u16* qrow = qbase + (size_t)(q0 + w * 32 + m * 16 + lrow) * 128 + lk * 8;
#pragma unroll
        for (int ks = 0; ks < 4; ks++) qf[m][ks] = *(const short8*)(qrow + ks * 32);
    }

    f32x4 o[2][8];
#pragma unroll
    for (int m = 0; m < 2; m++)
#pragma unroll
        for (int i = 0; i < 8; i++) o[m][i] = (f32x4){0.f, 0.f, 0.f, 0.f};
    float lsum[2][4] = {{0.f,0.f,0.f,0.f},{0.f,0.f,0.f,0.f}};

    int kR[4], kG[4], vR[4], vG[4];
#pragma unroll
    for (int i = 0; i < 4; i++) {
        int c = i * 256 + t;
        kR[i] = c >> 4; kG[i] = (c & 15) ^ (kR[i] & 7);
        vR[i] = c >> 3; vG[i] = (c & 7)  ^ (vR[i] & 7);
    }
    char* Ksb = (char*)Ks + w * 1024;
    char* Vsb = (char*)Vs + w * 1024;
    u16* pw = &Ps[w][0];
    const int wrow_max = q0 + w * 32 + 31;

    const int nkt = 2 * qt + 2;
    for (int kt = 0; kt < nkt; kt++) {
        const int kv0 = kt * 64;
        __syncthreads();
#pragma unroll
        for (int i = 0; i < 4; i++)
            glds16(kbase + (size_t)(kv0 + kR[i]) * 128 + kG[i] * 8, Ksb + i * 4096);
#pragma unroll
        for (int i = 0; i < 4; i++)
            glds16(vtbase + (size_t)vR[i] * 2048 + kv0 + vG[i] * 8, Vsb + i * 4096);
        __syncthreads();

        if (kv0 > wrow_max) continue;

        f32x4 s[2][4];
#pragma unroll
        for (int m = 0; m < 2; m++)
#pragma unroll
            for (int i = 0; i < 4; i++) s[m][i] = (f32x4){0.f, 0.f, 0.f, 0.f};
        __builtin_amdgcn_s_setprio(1);
#pragma unroll
        for (int ks = 0; ks < 4; ks++) {
#pragma unroll
            for (int nt = 0; nt < 4; nt++) {
                int r = nt * 16 + lrow;
                int sl = (ks * 4 + lk) ^ (r & 7);
                short8 kf = *(const short8*)&Ks[r * 128 + sl * 8];
                s[0][nt] = MFMA_BF16(qf[0][ks], kf, s[0][nt]);
                s[1][nt] = MFMA_BF16(qf[1][ks], kf, s[1][nt]);
            }
        }
        __builtin_amdgcn_s_setprio(0);

#pragma unroll
        for (int m = 0; m < 2; m++) {
            const int rowbase = q0 + w * 32 + m * 16;
            if (kv0 + 63 > rowbase) {
#pragma unroll
                for (int nt = 0; nt < 4; nt++) {
                    int cg = kv0 + nt * 16 + lrow;
#pragma unroll
                    for (int r = 0; r < 4; r++)
                        if (cg > rowbase + lk * 4 + r) s[m][nt][r] = -1e30f;
                }
            }
#pragma unroll
            for (int nt = 0; nt < 4; nt++)
#pragma unroll
                for (int r = 0; r < 4; r++) {
                    float pv = __expf(s[m][nt][r]);
                    s[m][nt][r] = pv;
                    lsum[m][r] += pv;
                    pw[(m * 16 + lk * 4 + r) * 72 + nt * 16 + lrow] = f2bf(pv);
                }
        }
        asm volatile("s_waitcnt lgkmcnt(0)" ::: "memory");

        __builtin_amdgcn_s_setprio(1);
#pragma unroll
        for (int k2 = 0; k2 < 2; k2++) {
            short8 pf0 = *(const short8*)&pw[lrow * 72 + k2 * 32 + lk * 8];
            short8 pf1 = *(const short8*)&pw[(16 + lrow) * 72 + k2 * 32 + lk * 8];
#pragma unroll
            for (int nt = 0; nt < 8; nt++) {
                int rr = nt * 16 + lrow;
                int sl = (k2 * 4 + lk) ^ (rr & 7);
                short8 vf = *(const short8*)&Vs[rr * 64 + sl * 8];
                o[0][nt] = MFMA_BF16(pf0, vf, o[0][nt]);
                o[1][nt] = MFMA_BF16(pf1, vf, o[1][nt]);
            }
        }
        __builtin_amdgcn_s_setprio(0);
    }

#pragma unroll
    for (int m = 0; m < 2; m++)
#pragma unroll
        for (int r = 0; r < 4; r++) {
            float v = lsum[m][r];
            v += __shfl_xor(v, 1, 64);
            v += __shfl_xor(v, 2, 64);
            v += __shfl_xor(v, 4, 64);
            v += __shfl_xor(v, 8, 64);
            lsum[m][r] = 1.0f / v;
        }
#pragma unroll
    for (int m = 0; m < 2; m++)
#pragma unroll
        for (int nt = 0; nt < 8; nt++)
#pragma unroll
            for (int r = 0; r < 4; r++) {
                int tok = q0 + w * 32 + m * 16 + lk * 4 + r;
                size_t off = ((size_t)b * 2048 + tok) * 4096 + h * 128 + nt * 16 + lrow;
                ao[off] = f2bf(o[m][nt][r] * lsum[m][r]);
            }
}

// ---------------- launcher ----------------
extern "C" void kernel_launch(void* const* d_in, const int* in_sizes, int n_in,
                              void* d_out, int out_size, void* d_ws, size_t ws_size,
                              hipStream_t stream)
{
    (void)in_sizes; (void)n_in; (void)out_size; (void)ws_size;
    const float* hidden = (const float*)d_in[0];
    const float* cosb   = (const float*)d_in[1];
    const float* sinb   = (const float*)d_in[2];
    const float* wq     = (const float*)d_in[3];
    const float* wk     = (const float*)d_in[4];
    const float* wv     = (const float*)d_in[5];
    const float* wo     = (const float*)d_in[6];
    const float* qg     = (const float*)d_in[7];
    const float* kg     = (const float*)d_in[8];

    float* out   = (float*)d_out;                    // (2,2048,2560)
    float* k_out = out + (size_t)2 * 2048 * 2560;    // (2,8,2048,128)
    float* v_out = k_out + (size_t)2 * 8 * 2048 * 128;

    // workspace layout (bf16 elements)
    u16* hid_b = (u16*)d_ws;                  // 4096x2560
    u16* w_b   = hid_b + 10485760;            // 6144x2560 (wq|wk|wv)
    u16* wo_b  = w_b   + 15728640;            // 2560x4096
    u16* q_b   = wo_b  + 10485760;            // (2,32,2048,128)
    u16* k_b   = q_b   + 16777216;            // (2,8,2048,128)
    u16* vt_b  = k_b   + 4194304;             // (2,8,128,2048)
    u16* qkv_b = vt_b  + 4194304;             // 4096x6144
    u16* ao_b  = hid_b;                       // alias: hid_b+w_b dead after QKV

    cvt_all<<<35840, 256, 0, stream>>>(hidden, hid_b, wq, w_b,
                                       wk, w_b + 10485760, wv, w_b + 13107200,
                                       wo, wo_b);

    // QKV: M=4096, N=6144, K=2560 -> bf16 qkv_b ; 256x192 tiles, 512 blocks
    gemm192<<<dim3(512), 512, 0, stream>>>(hid_b, w_b, qkv_b,
                                           2560, 2560, 2560, 6144);
    norm_rope_qk<<<40960, 256, 0, stream>>>(qkv_b, cosb, sinb, qg, kg,
                                            q_b, k_b, k_out);
    v_pack<<<dim3(32, 16), 256, 0, stream>>>(qkv_b, v_out, vt_b);
    attn_kernel<<<dim3(64, 16), 256, 0, stream>>>(q_b, k_b, vt_b, ao_b);
    // out-proj: M=4096, N=2560, K=4096 -> fp32 d_out ; grid 16*10=160 (%8==0)
    gemm8<false><<<dim3(160), 512, 0, stream>>>(ao_b, wo_b, out,
                                                4096, 4096, 4096, 2560, 10);
}